// Round 1
// 501.546 us; speedup vs baseline: 1.0488x; 1.0488x over previous
//
#include <hip/hip_runtime.h>

// ---------------------------------------------------------------------------
// Fused 3x3 valid conv (64->128) + bias + *2 + min over oc.
// Implicit GEMM, mfma_f32_32x32x16_bf16 (2495 TF ceiling vs 2075 for 16x16).
// Block: 256 thr (4 waves), tile 16H x 16W x 128 oc. Wave: rows wv*4..wv*4+3
// as 2 M-tiles (M=32 = 2 rows x 16 cols) x 4 N-tiles (32 oc), acc 128 regs.
// K = 576 split as [2 ic-chunks of 32] x [3 kh groups] x [3 kw taps x 2 K=16].
// Pipeline: wl double-buffered; next phase's W staged via global_load_lds
// (width 16) issued at the START of the current compute phase -> the loads
// have the whole MFMA phase to land; ONE barrier per phase (was 2 + serial
// reg-staged W between them = the 23%-MfmaUtil serialization).
// LDS 69,888 B (2 blocks/CU = 140 KB < 160 KB):
//   xs [18 row][18 col][32 ic] bf16, octet swizzle (o)^((col>>1)&3)^(row&3)
//   wl [2 buf][3 tt][4 n][2 ch][32 oc][2 h][8] bf16 (linear per phase block)
// R3 lesson kept: x staging px-major (lane quads cover one 64B line).
// R2 lesson kept: no big register prefetch against the 128-reg acc tile.
// ---------------------------------------------------------------------------

#define XR 18
#define XC 18
#define XTILE_SH (XR * XC * 32)          // 10368 shorts = 20736 B
#define WPH_SH (3 * 4 * 2 * 32 * 2 * 8)  // 12288 shorts = 24576 B per phase

typedef __attribute__((ext_vector_type(8))) short short8;
typedef __attribute__((ext_vector_type(16))) float f32x16;
typedef __attribute__((ext_vector_type(4))) float f4;

__device__ __forceinline__ unsigned short f2bf(float f) {
  unsigned int u = __builtin_bit_cast(unsigned int, f);
  u += 0x7FFFu + ((u >> 16) & 1u);  // round-to-nearest-even
  return (unsigned short)(u >> 16);
}
__device__ __forceinline__ unsigned int pk2(float lo, float hi) {
  return (unsigned int)f2bf(lo) | ((unsigned int)f2bf(hi) << 16);
}

// x LDS put: (row, col, ic-pair) -> swizzled dword address.
__device__ __forceinline__ void xput(unsigned short* xs, int row, int col,
                                     int pair, unsigned int pk) {
  int o = ((pair >> 2) ^ ((col >> 1) & 3) ^ (row & 3));
  int off = ((row * XC + col) << 5) + (o << 3) + ((pair & 3) << 1);
  *(unsigned int*)&xs[off] = pk;
}

typedef __attribute__((address_space(1))) const unsigned int as1_uint;
typedef __attribute__((address_space(3))) unsigned int as3_uint;
__device__ __forceinline__ void gload_lds16(const void* g, void* l) {
  __builtin_amdgcn_global_load_lds((as1_uint*)g, (as3_uint*)l, 16, 0, 0);
}

// W fp32 [oc][ic64][kh][kw] -> ws bf16 linear
// [pg = c*3+g][tt][n][ch][ocl32][h][s8]: value = w[n*32+ocl][c*32+ch*16+h*8+s][g][tt]
__global__ void repack_w(const float* __restrict__ w,
                         unsigned short* __restrict__ ws) {
  int idx = blockIdx.x * 256 + threadIdx.x;  // 73728 exact
  int s   = idx & 7;
  int h   = (idx >> 3) & 1;
  int ocl = (idx >> 4) & 31;
  int ch  = (idx >> 9) & 1;
  int n   = (idx >> 10) & 3;
  int rest = idx >> 12;  // 0..17 = pg*3 + tt
  int tt = rest % 3;
  int pg = rest / 3;
  int c = pg / 3, g = pg % 3;
  int oc = n * 32 + ocl;
  int ic = c * 32 + ch * 16 + h * 8 + s;
  ws[idx] = f2bf(w[oc * 576 + ic * 9 + g * 3 + tt]);
}

__global__ __launch_bounds__(256, 2) void conv_min_kernel(
    const float* __restrict__ x, const unsigned short* __restrict__ ws,
    const float* __restrict__ bias, float* __restrict__ out) {
  __shared__ unsigned short xs[XTILE_SH];
  __shared__ unsigned short wl[2 * WPH_SH];  // 49152 B double buffer

  const int tid  = threadIdx.x;
  const int wv   = tid >> 6;
  const int lane = tid & 63;
  const int cl   = lane & 15;
  const int ro   = (lane >> 4) & 1;
  const int hi   = lane >> 5;
  const int ocl  = lane & 31;

  const int W0 = blockIdx.x * 16;
  const int H0 = blockIdx.y * 16;
  const int b  = blockIdx.z;
  const float* xb = x + (size_t)b * 64 * 65536;

  f32x16 acc[2][4];
#pragma unroll
  for (int mt = 0; mt < 2; ++mt)
#pragma unroll
    for (int n = 0; n < 4; ++n)
#pragma unroll
      for (int r = 0; r < 16; ++r) acc[mt][n][r] = 0.f;

  // ---- x ic-chunk stage, px-major (coalesced); unchanged proven path ----
  auto stage_x = [&](int c) {
    // Main: 16 ic-pairs x 18 rows x 4 col-groups = 1152 float4 items.
    for (int i = tid; i < 1152; i += 256) {
      int g4   = i & 3;
      int r2   = i >> 2;            // pair*18 + row
      int row  = r2 % 18;
      int pair = r2 / 18;
      int gr = min(H0 + row, 255);  // clamped rows feed only discarded oh
      const float* p =
          xb + (size_t)(c * 32 + pair * 2) * 65536 + gr * 256 + W0 + g4 * 4;
      f4 a = *(const f4*)p;
      f4 d = *(const f4*)(p + 65536);
#pragma unroll
      for (int e = 0; e < 4; ++e)
        xput(xs, row, g4 * 4 + e, pair, pk2(a[e], d[e]));
    }
    // Ragged cols 16,17 (col-clamped: feeds only ow >= 254, never stored).
    for (int i = tid; i < 288; i += 256) {
      int row = i % 18, pair = i / 18;
      int gr = min(H0 + row, 255);
      int gc = min(W0 + 16, 254);
      const float* p =
          xb + (size_t)(c * 32 + pair * 2) * 65536 + gr * 256 + gc;
      float2 a = *(const float2*)p;
      float2 d = *(const float2*)(p + 65536);
      xput(xs, row, 16, pair, pk2(a.x, d.x));
      xput(xs, row, 17, pair, pk2(a.y, d.y));
    }
  };

  // ---- W stage: pure global_load_lds, linear 24576 B phase block ----
  auto stage_w = [&](int pg, unsigned short* dst) {
    const unsigned short* src = ws + pg * WPH_SH;
#pragma unroll
    for (int i = 0; i < 6; ++i) {
      int j = i * 256 + tid;  // 16B chunk index, 0..1535
      gload_lds16(src + j * 8, dst + j * 8);
    }
  };

  // ---- prologue ----
  stage_w(0, wl);
  stage_x(0);
  __syncthreads();  // drains vmcnt(0): wl[0] + x regs already consumed

#pragma unroll
  for (int pg = 0; pg < 6; ++pg) {
    const int g = pg % 3;
    const unsigned short* wc = wl + (pg & 1) * WPH_SH;
    // Issue next phase's W loads FIRST: they land during this compute phase,
    // so the barrier's vmcnt(0) drain is free (T3/T4 minimum-2-phase).
    if (pg < 5) stage_w(pg + 1, wl + ((pg + 1) & 1) * WPH_SH);

    __builtin_amdgcn_s_setprio(1);
#pragma unroll
    for (int tt = 0; tt < 3; ++tt) {
#pragma unroll
      for (int ch = 0; ch < 2; ++ch) {
        short8 bf[4];
#pragma unroll
        for (int n = 0; n < 4; ++n)
          bf[n] = *(const short8*)&wc[((tt * 4 + n) * 2 + ch) * 512 +
                                      ocl * 16 + hi * 8];
#pragma unroll
        for (int mt = 0; mt < 2; ++mt) {
          int rowx = wv * 4 + mt * 2 + ro + g;
          int colx = cl + tt;
          int o    = ch * 2 + hi;  // ic octet
          short8 af = *(const short8*)&xs[((rowx * XC + colx) << 5) +
                                          ((o ^ ((colx >> 1) & 3) ^
                                            (rowx & 3)) << 3)];
#pragma unroll
          for (int n = 0; n < 4; ++n)
            acc[mt][n] = __builtin_amdgcn_mfma_f32_32x32x16_bf16(
                af, bf[n], acc[mt][n], 0, 0, 0);
        }
      }
    }
    __builtin_amdgcn_s_setprio(0);

    if (pg == 2) {
      __syncthreads();  // all waves done reading xs(c=0); wl[1] landed
      stage_x(1);
      __syncthreads();
    } else if (pg < 5) {
      __syncthreads();  // cheap drain: next-W loads issued a full phase ago
    }
  }

  // ---- epilogue: min over 128 oc of (acc + bias), then *2, store ----
  float bv[4];
#pragma unroll
  for (int n = 0; n < 4; ++n) bv[n] = bias[n * 32 + ocl];

#pragma unroll
  for (int mt = 0; mt < 2; ++mt) {
#pragma unroll
    for (int r = 0; r < 16; ++r) {
      float v = acc[mt][0][r] + bv[0];
      v = fminf(v, acc[mt][1][r] + bv[1]);
      v = fminf(v, acc[mt][2][r] + bv[2]);
      v = fminf(v, acc[mt][3][r] + bv[3]);
      // reduce over the 32 lanes of this half-wave (oc dimension)
      v = fminf(v, __shfl_xor(v, 1));
      v = fminf(v, __shfl_xor(v, 2));
      v = fminf(v, __shfl_xor(v, 4));
      v = fminf(v, __shfl_xor(v, 8));
      v = fminf(v, __shfl_xor(v, 16));
      // C/D map (verified): row m = (r&3) + 8*(r>>2) + 4*hi, col = lane&31
      int m  = (r & 3) + 8 * (r >> 2) + 4 * hi;
      int oh = H0 + wv * 4 + mt * 2 + (m >> 4);
      int ow = W0 + (m & 15);
      if (ocl == 0 && oh < 254 && ow < 254)
        out[((size_t)b * 254 + oh) * 254 + ow] = v * 2.0f;
    }
  }
}

extern "C" void kernel_launch(void* const* d_in, const int* in_sizes, int n_in,
                              void* d_out, int out_size, void* d_ws,
                              size_t ws_size, hipStream_t stream) {
  const float* x    = (const float*)d_in[0];
  const float* w    = (const float*)d_in[1];
  const float* bias = (const float*)d_in[2];
  float* out        = (float*)d_out;
  unsigned short* ws = (unsigned short*)d_ws;  // 147,456 B bf16 weights

  // ws re-poisoned before every call -> repack every call (same work/call).
  repack_w<<<288, 256, 0, stream>>>(w, ws);

  dim3 grid(16, 16, 16);  // 16x16 tiles over 254x254, batch 16
  conv_min_kernel<<<grid, 256, 0, stream>>>(x, ws, bias, out);
}

// Round 2
// 456.438 us; speedup vs baseline: 1.1525x; 1.0988x over previous
//
#include <hip/hip_runtime.h>

// ---------------------------------------------------------------------------
// Fused 3x3 valid conv (64->128) + bias + *2 + min over oc.
// Implicit GEMM, mfma_f32_32x32x16_bf16.
// Block: 256 thr (4 waves), tile 16H x 16W x 128 oc. Wave: rows wv*4..wv*4+3
// as 2 M-tiles (M=32 = 2 rows x 16 cols) x 4 N-tiles (32 oc), acc 128 regs.
// K = 576 split as [2 ic-chunks of 32] x [3 kh groups] x [3 kw taps x 2 K=16].
// Pipeline: wl double-buffered; next phase's W staged via global_load_lds
// issued at the START of the current compute phase; ONE barrier per phase.
// R4 lesson: wl layout must be LANE-ordered [tt][ch][n][lane][16B] — the
// [oc][hi] order gave a 32B lane stride on ds_read_b128 (21.9M bank-conflict
// cycles). Lane-consecutive 16B chunks are conflict-free with NO swizzle,
// and stay global_load_lds-compatible (linear both sides, rule #21).
// R4b: x-staging ds_write banks: pair&3 was wave-constant (16-way) -> plo
// interleave puts 4 pair-lsb values in every wave (4-way), same coverage,
// same 64B-line quad coalescing (R3 lesson preserved).
// R4c: epilogue slot-folding butterfly: 32 shfl + 4 store insts per wave
// (was 160 shfl + 64 stores), all min-reduce work register-resident.
// R3 lesson kept: x staging px-major. R2 lesson kept: no big reg prefetch
// against the 128-reg acc tile.
// LDS 69,888 B (2 blocks/CU):
//   xs [18 row][18 col][32 ic] bf16, octet swizzle o^((col>>1)&3)^(row&3)
//   wl [2 buf][3 tt][2 ch][4 n][64 lane][8] bf16 (linear, lane-ordered)
// ---------------------------------------------------------------------------

#define XR 18
#define XC 18
#define XTILE_SH (XR * XC * 32)          // 10368 shorts = 20736 B
#define WPH_SH (3 * 2 * 4 * 64 * 8)      // 12288 shorts = 24576 B per phase

typedef __attribute__((ext_vector_type(8))) short short8;
typedef __attribute__((ext_vector_type(16))) float f32x16;
typedef __attribute__((ext_vector_type(4))) float f4;

__device__ __forceinline__ unsigned short f2bf(float f) {
  unsigned int u = __builtin_bit_cast(unsigned int, f);
  u += 0x7FFFu + ((u >> 16) & 1u);  // round-to-nearest-even
  return (unsigned short)(u >> 16);
}
__device__ __forceinline__ unsigned int pk2(float lo, float hi) {
  return (unsigned int)f2bf(lo) | ((unsigned int)f2bf(hi) << 16);
}

// x LDS put: (row, col, ic-pair) -> swizzled dword address.
__device__ __forceinline__ void xput(unsigned short* xs, int row, int col,
                                     int pair, unsigned int pk) {
  int o = ((pair >> 2) ^ ((col >> 1) & 3) ^ (row & 3));
  int off = ((row * XC + col) << 5) + (o << 3) + ((pair & 3) << 1);
  *(unsigned int*)&xs[off] = pk;
}

typedef __attribute__((address_space(1))) const unsigned int as1_uint;
typedef __attribute__((address_space(3))) unsigned int as3_uint;
__device__ __forceinline__ void gload_lds16(const void* g, void* l) {
  __builtin_amdgcn_global_load_lds((as1_uint*)g, (as3_uint*)l, 16, 0, 0);
}

// W fp32 [oc][ic64][kh][kw] -> ws bf16 lane-ordered fragments:
// idx = ((((pg*3+tt)*2+ch)*4+n)*64+l)*8+e
// value = w[oc = n*32+(l&31)][ic = c*32+ch*16+(l>>5)*8+e][kh=g][kw=tt]
__global__ void repack_w(const float* __restrict__ w,
                         unsigned short* __restrict__ ws) {
  int idx = blockIdx.x * 256 + threadIdx.x;  // 73728 exact
  int e  = idx & 7;
  int l  = (idx >> 3) & 63;
  int n  = (idx >> 9) & 3;
  int ch = (idx >> 11) & 1;
  int rest = idx >> 12;  // 0..17 = pg*3 + tt
  int tt = rest % 3;
  int pg = rest / 3;
  int c = pg / 3, g = pg % 3;
  int oc = n * 32 + (l & 31);
  int ic = c * 32 + ch * 16 + (l >> 5) * 8 + e;
  ws[idx] = f2bf(w[oc * 576 + ic * 9 + g * 3 + tt]);
}

__global__ __launch_bounds__(256, 2) void conv_min_kernel(
    const float* __restrict__ x, const unsigned short* __restrict__ ws,
    const float* __restrict__ bias, float* __restrict__ out) {
  __shared__ unsigned short xs[XTILE_SH];
  __shared__ unsigned short wl[2 * WPH_SH];  // 49152 B double buffer

  const int tid  = threadIdx.x;
  const int wv   = tid >> 6;
  const int lane = tid & 63;
  const int cl   = lane & 15;
  const int ro   = (lane >> 4) & 1;
  const int hi   = lane >> 5;

  const int W0 = blockIdx.x * 16;
  const int H0 = blockIdx.y * 16;
  const int b  = blockIdx.z;
  const float* xb = x + (size_t)b * 64 * 65536;

  f32x16 acc[2][4];
#pragma unroll
  for (int mt = 0; mt < 2; ++mt)
#pragma unroll
    for (int n = 0; n < 4; ++n)
#pragma unroll
      for (int r = 0; r < 16; ++r) acc[mt][n][r] = 0.f;

  // ---- x ic-chunk stage, px-major (coalesced) ----
  // Main: 16 ic-pairs x 18 rows x 4 col-groups = 1152 float4 items.
  // plo interleave: pair&3 varies within each wave -> LDS write banks
  // spread 4->16 (16-way -> 4-way conflicts). Coverage & coalescing same.
  auto stage_x = [&](int c) {
    for (int i = tid; i < 1152; i += 256) {
      int g4   = i & 3;
      int plo  = (i >> 2) & 3;
      int q    = i >> 4;            // 0..71
      int row  = q % 18;
      int phi  = q / 18;            // 0..3
      int pair = phi * 4 + plo;
      int gr = min(H0 + row, 255);  // clamped rows feed only discarded oh
      const float* p =
          xb + (size_t)(c * 32 + pair * 2) * 65536 + gr * 256 + W0 + g4 * 4;
      f4 a = *(const f4*)p;
      f4 d = *(const f4*)(p + 65536);
#pragma unroll
      for (int e = 0; e < 4; ++e)
        xput(xs, row, g4 * 4 + e, pair, pk2(a[e], d[e]));
    }
    // Ragged cols 16,17 (col-clamped: feeds only ow >= 254, never stored).
    for (int i = tid; i < 288; i += 256) {
      int row = i % 18, pair = i / 18;
      int gr = min(H0 + row, 255);
      int gc = min(W0 + 16, 254);
      const float* p =
          xb + (size_t)(c * 32 + pair * 2) * 65536 + gr * 256 + gc;
      float2 a = *(const float2*)p;
      float2 d = *(const float2*)(p + 65536);
      xput(xs, row, 16, pair, pk2(a.x, d.x));
      xput(xs, row, 17, pair, pk2(a.y, d.y));
    }
  };

  // ---- W stage: pure global_load_lds, linear 24576 B phase block ----
  auto stage_w = [&](int pg, unsigned short* dst) {
    const unsigned short* src = ws + pg * WPH_SH;
#pragma unroll
    for (int i = 0; i < 6; ++i) {
      int j = i * 256 + tid;  // 16B chunk index, 0..1535
      gload_lds16(src + j * 8, dst + j * 8);
    }
  };

  // ---- prologue ----
  stage_w(0, wl);
  stage_x(0);
  __syncthreads();  // drains vmcnt(0): wl[0] + x regs already consumed

#pragma unroll
  for (int pg = 0; pg < 6; ++pg) {
    const int g = pg % 3;
    const unsigned short* wc = wl + (pg & 1) * WPH_SH;
    // Issue next phase's W loads FIRST: they land during this compute phase,
    // so the barrier's vmcnt(0) drain is free (T3/T4 minimum-2-phase).
    if (pg < 5) stage_w(pg + 1, wl + ((pg + 1) & 1) * WPH_SH);

    __builtin_amdgcn_s_setprio(1);
#pragma unroll
    for (int tt = 0; tt < 3; ++tt) {
#pragma unroll
      for (int ch = 0; ch < 2; ++ch) {
        short8 bf[4];
#pragma unroll
        for (int n = 0; n < 4; ++n)
          bf[n] = *(const short8*)&wc[(((tt * 2 + ch) * 4 + n) << 9) +
                                      (lane << 3)];
#pragma unroll
        for (int mt = 0; mt < 2; ++mt) {
          int rowx = wv * 4 + mt * 2 + ro + g;
          int colx = cl + tt;
          int o    = ch * 2 + hi;  // ic octet
          short8 af = *(const short8*)&xs[((rowx * XC + colx) << 5) +
                                          ((o ^ ((colx >> 1) & 3) ^
                                            (rowx & 3)) << 3)];
#pragma unroll
          for (int n = 0; n < 4; ++n)
            acc[mt][n] = __builtin_amdgcn_mfma_f32_32x32x16_bf16(
                af, bf[n], acc[mt][n], 0, 0, 0);
        }
      }
    }
    __builtin_amdgcn_s_setprio(0);

    if (pg == 2) {
      __syncthreads();  // all waves done reading xs(c=0); wl[1] landed
      stage_x(1);
      __syncthreads();
    } else if (pg < 5) {
      __syncthreads();  // cheap drain: next-W loads issued a full phase ago
    }
  }

  // ---- epilogue: min over 128 oc of (acc + bias), then *2, store ----
  // Slot-folding butterfly: stage k exchanges the slot the PARTNER keeps
  // (z), receives partner's copy of OUR kept slot. After 4 stages lane
  // holds slot r = lane&15 = min over its 16-lane group; xor16 completes
  // the 32-lane (oc) reduce. 32 shfl/wave vs 160 before.
  float bv[4];
#pragma unroll
  for (int n = 0; n < 4; ++n) bv[n] = bias[n * 32 + (lane & 31)];

#pragma unroll
  for (int mt = 0; mt < 2; ++mt) {
    float v[16];
#pragma unroll
    for (int r = 0; r < 16; ++r) {
      float t0 = fminf(acc[mt][0][r] + bv[0], acc[mt][1][r] + bv[1]);
      float t1 = fminf(acc[mt][2][r] + bv[2], acc[mt][3][r] + bv[3]);
      v[r] = fminf(t0, t1);
    }
    float w8[8], w4[4], w2[2], w1;
#pragma unroll
    for (int j = 0; j < 8; ++j) {
      int s = lane & 1;
      float xk = s ? v[2 * j + 1] : v[2 * j];
      float zk = s ? v[2 * j] : v[2 * j + 1];
      w8[j] = fminf(xk, __shfl_xor(zk, 1));
    }
#pragma unroll
    for (int j = 0; j < 4; ++j) {
      int s = (lane >> 1) & 1;
      float xk = s ? w8[2 * j + 1] : w8[2 * j];
      float zk = s ? w8[2 * j] : w8[2 * j + 1];
      w4[j] = fminf(xk, __shfl_xor(zk, 2));
    }
#pragma unroll
    for (int j = 0; j < 2; ++j) {
      int s = (lane >> 2) & 1;
      float xk = s ? w4[2 * j + 1] : w4[2 * j];
      float zk = s ? w4[2 * j] : w4[2 * j + 1];
      w2[j] = fminf(xk, __shfl_xor(zk, 4));
    }
    {
      int s = (lane >> 3) & 1;
      float xk = s ? w2[1] : w2[0];
      float zk = s ? w2[0] : w2[1];
      w1 = fminf(xk, __shfl_xor(zk, 8));
    }
    w1 = fminf(w1, __shfl_xor(w1, 16));
    // lane holds slot r = lane&15; C/D map: m = (r&3) + 8*(r>>2) + 4*hi
    int r  = lane & 15;
    int m  = (r & 3) + 8 * (r >> 2) + 4 * hi;
    int oh = H0 + wv * 4 + mt * 2 + (m >> 4);
    int ow = W0 + (m & 15);
    if ((lane & 16) == 0 && oh < 254 && ow < 254)
      out[((size_t)b * 254 + oh) * 254 + ow] = w1 * 2.0f;
  }
}

extern "C" void kernel_launch(void* const* d_in, const int* in_sizes, int n_in,
                              void* d_out, int out_size, void* d_ws,
                              size_t ws_size, hipStream_t stream) {
  const float* x    = (const float*)d_in[0];
  const float* w    = (const float*)d_in[1];
  const float* bias = (const float*)d_in[2];
  float* out        = (float*)d_out;
  unsigned short* ws = (unsigned short*)d_ws;  // 147,456 B bf16 weights

  // ws re-poisoned before every call -> repack every call (same work/call).
  repack_w<<<288, 256, 0, stream>>>(w, ws);

  dim3 grid(16, 16, 16);  // 16x16 tiles over 254x254, batch 16
  conv_min_kernel<<<grid, 256, 0, stream>>>(x, ws, bias, out);
}